// Round 11
// baseline (394.910 us; speedup 1.0000x reference)
//
#include <hip/hip_runtime.h>
#include <hip/hip_bf16.h>

typedef __attribute__((ext_vector_type(4))) float floatx4;
typedef __attribute__((ext_vector_type(8))) int   intx8;

#define FP8_MAX_F 448.0f
#define SCALE_EPS 1e-7f

// ------ fused pre-pass: blocks 0-1791 absmax(x); blocks 1792-2047 quantize W ------------
__global__ void k_pre(const float* __restrict__ x, unsigned* __restrict__ amax, int n4,
                      const float* __restrict__ w, int* __restrict__ wq, int nw16) {
    if (blockIdx.x < 1792) {
        __shared__ float wmax[4];
        int tid = blockIdx.x * 256 + threadIdx.x;
        int stride = 1792 * 256;
        const float4* x4 = (const float4*)x;
        float m = 0.f;
        for (int i = tid; i < n4; i += stride) {
            float4 v = x4[i];
            m = fmaxf(fmaxf(fabsf(v.x), fabsf(v.y)),
                      fmaxf(m, fmaxf(fabsf(v.z), fabsf(v.w))));
        }
        #pragma unroll
        for (int off = 32; off > 0; off >>= 1) m = fmaxf(m, __shfl_xor(m, off, 64));
        if ((threadIdx.x & 63) == 0) wmax[threadIdx.x >> 6] = m;
        __syncthreads();
        if (threadIdx.x == 0) {
            float t = fmaxf(fmaxf(wmax[0], wmax[1]), fmaxf(wmax[2], wmax[3]));
            atomicMax(amax, __float_as_uint(t));
        }
    } else {
        int tid = (blockIdx.x - 1792) * 256 + threadIdx.x;
        int stride = 256 * 256;
        const float4* x4 = (const float4*)w;
        int4* q4 = (int4*)wq;
        for (int i = tid; i < nw16; i += stride) {
            float4 v0 = x4[4*i], v1 = x4[4*i+1], v2 = x4[4*i+2], v3 = x4[4*i+3];
            int4 o;
            o.x = __builtin_amdgcn_cvt_pk_fp8_f32(v0.x, v0.y, 0, false);
            o.x = __builtin_amdgcn_cvt_pk_fp8_f32(v0.z, v0.w, o.x, true);
            o.y = __builtin_amdgcn_cvt_pk_fp8_f32(v1.x, v1.y, 0, false);
            o.y = __builtin_amdgcn_cvt_pk_fp8_f32(v1.z, v1.w, o.y, true);
            o.z = __builtin_amdgcn_cvt_pk_fp8_f32(v2.x, v2.y, 0, false);
            o.z = __builtin_amdgcn_cvt_pk_fp8_f32(v2.z, v2.w, o.z, true);
            o.w = __builtin_amdgcn_cvt_pk_fp8_f32(v3.x, v3.y, 0, false);
            o.w = __builtin_amdgcn_cvt_pk_fp8_f32(v3.z, v3.w, o.w, true);
            q4[i] = o;
        }
    }
}

// ---------------- x: f32 -> e4m3 bytes (HW RNE), scale = max(absmax/448, eps) -------------
__global__ void k_quant_x(const float* __restrict__ x, int* __restrict__ xq,
                          const unsigned* __restrict__ amax, int n16) {
    float scale = fmaxf(__uint_as_float(*amax) / FP8_MAX_F, SCALE_EPS);
    int tid = blockIdx.x * blockDim.x + threadIdx.x;
    int stride = gridDim.x * blockDim.x;
    const float4* x4 = (const float4*)x;
    int4* q4 = (int4*)xq;
    for (int i = tid; i < n16; i += stride) {
        float4 v0 = x4[4*i], v1 = x4[4*i+1], v2 = x4[4*i+2], v3 = x4[4*i+3];
        int4 o;
        o.x = __builtin_amdgcn_cvt_pk_fp8_f32(v0.x / scale, v0.y / scale, 0, false);
        o.x = __builtin_amdgcn_cvt_pk_fp8_f32(v0.z / scale, v0.w / scale, o.x, true);
        o.y = __builtin_amdgcn_cvt_pk_fp8_f32(v1.x / scale, v1.y / scale, 0, false);
        o.y = __builtin_amdgcn_cvt_pk_fp8_f32(v1.z / scale, v1.w / scale, o.y, true);
        o.z = __builtin_amdgcn_cvt_pk_fp8_f32(v2.x / scale, v2.y / scale, 0, false);
        o.z = __builtin_amdgcn_cvt_pk_fp8_f32(v2.z / scale, v2.w / scale, o.z, true);
        o.w = __builtin_amdgcn_cvt_pk_fp8_f32(v3.x / scale, v3.y / scale, 0, false);
        o.w = __builtin_amdgcn_cvt_pk_fp8_f32(v3.z / scale, v3.w / scale, o.w, true);
        q4[i] = o;
    }
}

// ================= 128x128 MX-fp8 GEMM (r2 structure) at 5 blocks/CU =====================
// C[M,N] = ws * (A[M,K]fp8 . B[N,K]fp8^T) + bias.  Slab = 128 fp8-K (one 16x16x128 step).
// r10's kernel with __launch_bounds__(256,5): 5 x 32KB LDS = 160KB exactly; 64 VGPR
// -> 20 waves/CU. Co-resident blocks hide each other's DMA-drain + barrier convoys.
#define BM 128
#define BN 128
#define BKQ 128

__global__ __launch_bounds__(256, 5) void k_gemm_mx(
    const unsigned char* __restrict__ A, const unsigned char* __restrict__ B,
    const float* __restrict__ bias, const float* __restrict__ wscale,
    float* __restrict__ C, int M, int N, int K) {
    __shared__ __align__(16) unsigned char As[BM * BKQ];   // 16 KB
    __shared__ __align__(16) unsigned char Bs[BN * BKQ];   // 16 KB

    int nwg = gridDim.x;
    int bid = blockIdx.x;
    bid = (bid & 7) * (nwg >> 3) + (bid >> 3);   // XCD swizzle (nwg % 8 == 0)
    int ntn = N / BN;
    int tm = bid / ntn, tn = bid % ntn;
    int row0 = tm * BM, col0 = tn * BN;

    int tid = (int)threadIdx.x;
    int lane = tid & 63, wid = tid >> 6;
    int wr = wid >> 1, wc = wid & 1;             // 2x2 waves; per-wave 64x64
    int fr = lane & 15, g = lane >> 4;

    // staging: inst i writes physical chunks p = i*256 + tid (16B each), linear in LDS.
    int srow = tid >> 3;        // + i*32 -> physical row
    int scol = tid & 7;         // physical chunk col

    floatx4 acc[4][4];
    #pragma unroll
    for (int m = 0; m < 4; ++m)
        #pragma unroll
        for (int n = 0; n < 4; ++n) acc[m][n] = (floatx4)(0.f);

    for (int kt = 0; kt < K; kt += BKQ) {
        __syncthreads();
        #pragma unroll
        for (int i = 0; i < 4; ++i) {
            int r = i * 32 + srow;
            int c = scol ^ (r & 7);            // inverse-swizzled source chunk
            __builtin_amdgcn_global_load_lds(
                (const __attribute__((address_space(1))) void*)(A + (size_t)(row0 + r) * K + kt + c * 16),
                (__attribute__((address_space(3))) void*)(As + i * 4096 + wid * 1024), 16, 0, 0);
        }
        #pragma unroll
        for (int i = 0; i < 4; ++i) {
            int r = i * 32 + srow;
            int c = scol ^ (r & 7);
            __builtin_amdgcn_global_load_lds(
                (const __attribute__((address_space(1))) void*)(B + (size_t)(col0 + r) * K + kt + c * 16),
                (__attribute__((address_space(3))) void*)(Bs + i * 4096 + wid * 1024), 16, 0, 0);
        }
        __syncthreads();   // compiler drains vmcnt(0) before barrier -> LDS ready

        intx8 a[4], b[4];
        #pragma unroll
        for (int m = 0; m < 4; ++m) {
            int r = wr * 64 + m * 16 + fr;
            int c0 = (2 * g)     ^ (r & 7);
            int c1 = (2 * g + 1) ^ (r & 7);
            int4 lo = *(const int4*)(As + r * 128 + c0 * 16);
            int4 hi = *(const int4*)(As + r * 128 + c1 * 16);
            a[m] = (intx8){lo.x, lo.y, lo.z, lo.w, hi.x, hi.y, hi.z, hi.w};
        }
        #pragma unroll
        for (int n = 0; n < 4; ++n) {
            int r = wc * 64 + n * 16 + fr;
            int c0 = (2 * g)     ^ (r & 7);
            int c1 = (2 * g + 1) ^ (r & 7);
            int4 lo = *(const int4*)(Bs + r * 128 + c0 * 16);
            int4 hi = *(const int4*)(Bs + r * 128 + c1 * 16);
            b[n] = (intx8){lo.x, lo.y, lo.z, lo.w, hi.x, hi.y, hi.z, hi.w};
        }
        #pragma unroll
        for (int m = 0; m < 4; ++m)
            #pragma unroll
            for (int n = 0; n < 4; ++n)
                acc[m][n] = __builtin_amdgcn_mfma_scale_f32_16x16x128_f8f6f4(
                    a[m], b[n], acc[m][n], 0, 0,           // cbsz=fp8, blgp=fp8
                    0, 0x7F7F7F7F, 0, 0x7F7F7F7F);         // E8M0 scales = 1.0
    }

    // epilogue: C/D layout (shape-determined): col=lane&15, row=(lane>>4)*4+j
    float wsv = *wscale;
    int crow = g * 4;
    int ccol = fr;
    float bv[4];
    #pragma unroll
    for (int n = 0; n < 4; ++n) bv[n] = bias[col0 + wc * 64 + n * 16 + ccol];
    #pragma unroll
    for (int m = 0; m < 4; ++m) {
        int r = row0 + wr * 64 + m * 16 + crow;
        #pragma unroll
        for (int n = 0; n < 4; ++n) {
            int c = col0 + wc * 64 + n * 16 + ccol;
            #pragma unroll
            for (int j = 0; j < 4; ++j)
                C[(long)(r + j) * N + c] = acc[m][n][j] * wsv + bv[n];
        }
    }
}

extern "C" void kernel_launch(void* const* d_in, const int* in_sizes, int n_in,
                              void* d_out, int out_size, void* d_ws, size_t ws_size,
                              hipStream_t stream) {
    const float* x      = (const float*)d_in[0];
    const float* w      = (const float*)d_in[1];
    const float* wscale = (const float*)d_in[2];
    const float* bias   = (const float*)d_in[3];
    float* out = (float*)d_out;

    const int K = 2048, N = 2048;
    const int M = in_sizes[0] / K;     // 16384

    unsigned char* ws = (unsigned char*)d_ws;
    unsigned* amax = (unsigned*)ws;                          // 4 B
    int* wq = (int*)(ws + 1024);                             // N*K   = 4.2 MB fp8
    int* xq = (int*)(ws + 1024 + (size_t)N * K);             // M*K   = 33.5 MB fp8

    hipMemsetAsync(amax, 0, 4, stream);
    k_pre<<<2048, 256, 0, stream>>>(x, amax, (M * K) / 4, w, wq, (N * K) / 16);
    k_quant_x<<<2048, 256, 0, stream>>>(x, xq, amax, (M * K) / 16);

    int grid = (M / BM) * (N / BN);    // 128 * 16 = 2048
    k_gemm_mx<<<grid, 256, 0, stream>>>((const unsigned char*)xq, (const unsigned char*)wq,
                                        bias, wscale, out, M, N, K);
}

// Round 12
// 144.731 us; speedup vs baseline: 2.7286x; 2.7286x over previous
//
#include <hip/hip_runtime.h>
#include <hip/hip_bf16.h>

typedef __attribute__((ext_vector_type(4))) float floatx4;
typedef __attribute__((ext_vector_type(8))) int   intx8;

#define FP8_MAX_F 448.0f
#define SCALE_EPS 1e-7f

// ------ fused pre-pass: blocks 0-1791 absmax(x); blocks 1792-2047 quantize W ------------
__global__ void k_pre(const float* __restrict__ x, unsigned* __restrict__ amax, int n4,
                      const float* __restrict__ w, int* __restrict__ wq, int nw16) {
    if (blockIdx.x < 1792) {
        __shared__ float wmax[4];
        int tid = blockIdx.x * 256 + threadIdx.x;
        int stride = 1792 * 256;
        const float4* x4 = (const float4*)x;
        float m = 0.f;
        for (int i = tid; i < n4; i += stride) {
            float4 v = x4[i];
            m = fmaxf(fmaxf(fabsf(v.x), fabsf(v.y)),
                      fmaxf(m, fmaxf(fabsf(v.z), fabsf(v.w))));
        }
        #pragma unroll
        for (int off = 32; off > 0; off >>= 1) m = fmaxf(m, __shfl_xor(m, off, 64));
        if ((threadIdx.x & 63) == 0) wmax[threadIdx.x >> 6] = m;
        __syncthreads();
        if (threadIdx.x == 0) {
            float t = fmaxf(fmaxf(wmax[0], wmax[1]), fmaxf(wmax[2], wmax[3]));
            atomicMax(amax, __float_as_uint(t));
        }
    } else {
        int tid = (blockIdx.x - 1792) * 256 + threadIdx.x;
        int stride = 256 * 256;
        const float4* x4 = (const float4*)w;
        int4* q4 = (int4*)wq;
        for (int i = tid; i < nw16; i += stride) {
            float4 v0 = x4[4*i], v1 = x4[4*i+1], v2 = x4[4*i+2], v3 = x4[4*i+3];
            int4 o;
            o.x = __builtin_amdgcn_cvt_pk_fp8_f32(v0.x, v0.y, 0, false);
            o.x = __builtin_amdgcn_cvt_pk_fp8_f32(v0.z, v0.w, o.x, true);
            o.y = __builtin_amdgcn_cvt_pk_fp8_f32(v1.x, v1.y, 0, false);
            o.y = __builtin_amdgcn_cvt_pk_fp8_f32(v1.z, v1.w, o.y, true);
            o.z = __builtin_amdgcn_cvt_pk_fp8_f32(v2.x, v2.y, 0, false);
            o.z = __builtin_amdgcn_cvt_pk_fp8_f32(v2.z, v2.w, o.z, true);
            o.w = __builtin_amdgcn_cvt_pk_fp8_f32(v3.x, v3.y, 0, false);
            o.w = __builtin_amdgcn_cvt_pk_fp8_f32(v3.z, v3.w, o.w, true);
            q4[i] = o;
        }
    }
}

// ---------------- x: f32 -> e4m3 bytes (HW RNE), scale = max(absmax/448, eps) -------------
__global__ void k_quant_x(const float* __restrict__ x, int* __restrict__ xq,
                          const unsigned* __restrict__ amax, int n16) {
    float scale = fmaxf(__uint_as_float(*amax) / FP8_MAX_F, SCALE_EPS);
    int tid = blockIdx.x * blockDim.x + threadIdx.x;
    int stride = gridDim.x * blockDim.x;
    const float4* x4 = (const float4*)x;
    int4* q4 = (int4*)xq;
    for (int i = tid; i < n16; i += stride) {
        float4 v0 = x4[4*i], v1 = x4[4*i+1], v2 = x4[4*i+2], v3 = x4[4*i+3];
        int4 o;
        o.x = __builtin_amdgcn_cvt_pk_fp8_f32(v0.x / scale, v0.y / scale, 0, false);
        o.x = __builtin_amdgcn_cvt_pk_fp8_f32(v0.z / scale, v0.w / scale, o.x, true);
        o.y = __builtin_amdgcn_cvt_pk_fp8_f32(v1.x / scale, v1.y / scale, 0, false);
        o.y = __builtin_amdgcn_cvt_pk_fp8_f32(v1.z / scale, v1.w / scale, o.y, true);
        o.z = __builtin_amdgcn_cvt_pk_fp8_f32(v2.x / scale, v2.y / scale, 0, false);
        o.z = __builtin_amdgcn_cvt_pk_fp8_f32(v2.z / scale, v2.w / scale, o.z, true);
        o.w = __builtin_amdgcn_cvt_pk_fp8_f32(v3.x / scale, v3.y / scale, 0, false);
        o.w = __builtin_amdgcn_cvt_pk_fp8_f32(v3.z / scale, v3.w / scale, o.w, true);
        q4[i] = o;
    }
}

// ================= 128x128 MX-fp8 GEMM (r2 structure) at 4 blocks/CU =====================
// C[M,N] = ws * (A[M,K]fp8 . B[N,K]fp8^T) + bias.  Slab = 128 fp8-K (one 16x16x128 step).
// Best-known config (r10): single 32KB LDS buffer, __syncthreads-drained staging, c^(r&7)
// chunk swizzle, __launch_bounds__(256,4). DO NOT raise the min-waves bound: (256,5)
// squeezed VGPR to 48 < the 64-reg accumulator -> scratch spill, 4x regression (r11).
#define BM 128
#define BN 128
#define BKQ 128

__global__ __launch_bounds__(256, 4) void k_gemm_mx(
    const unsigned char* __restrict__ A, const unsigned char* __restrict__ B,
    const float* __restrict__ bias, const float* __restrict__ wscale,
    float* __restrict__ C, int M, int N, int K) {
    __shared__ __align__(16) unsigned char As[BM * BKQ];   // 16 KB
    __shared__ __align__(16) unsigned char Bs[BN * BKQ];   // 16 KB

    int nwg = gridDim.x;
    int bid = blockIdx.x;
    bid = (bid & 7) * (nwg >> 3) + (bid >> 3);   // XCD swizzle (nwg % 8 == 0)
    int ntn = N / BN;
    int tm = bid / ntn, tn = bid % ntn;
    int row0 = tm * BM, col0 = tn * BN;

    int tid = (int)threadIdx.x;
    int lane = tid & 63, wid = tid >> 6;
    int wr = wid >> 1, wc = wid & 1;             // 2x2 waves; per-wave 64x64
    int fr = lane & 15, g = lane >> 4;

    // staging: inst i writes physical chunks p = i*256 + tid (16B each), linear in LDS.
    int srow = tid >> 3;        // + i*32 -> physical row
    int scol = tid & 7;         // physical chunk col

    floatx4 acc[4][4];
    #pragma unroll
    for (int m = 0; m < 4; ++m)
        #pragma unroll
        for (int n = 0; n < 4; ++n) acc[m][n] = (floatx4)(0.f);

    for (int kt = 0; kt < K; kt += BKQ) {
        __syncthreads();
        #pragma unroll
        for (int i = 0; i < 4; ++i) {
            int r = i * 32 + srow;
            int c = scol ^ (r & 7);            // inverse-swizzled source chunk
            __builtin_amdgcn_global_load_lds(
                (const __attribute__((address_space(1))) void*)(A + (size_t)(row0 + r) * K + kt + c * 16),
                (__attribute__((address_space(3))) void*)(As + i * 4096 + wid * 1024), 16, 0, 0);
        }
        #pragma unroll
        for (int i = 0; i < 4; ++i) {
            int r = i * 32 + srow;
            int c = scol ^ (r & 7);
            __builtin_amdgcn_global_load_lds(
                (const __attribute__((address_space(1))) void*)(B + (size_t)(col0 + r) * K + kt + c * 16),
                (__attribute__((address_space(3))) void*)(Bs + i * 4096 + wid * 1024), 16, 0, 0);
        }
        __syncthreads();   // compiler drains vmcnt(0) before barrier -> LDS ready

        intx8 a[4], b[4];
        #pragma unroll
        for (int m = 0; m < 4; ++m) {
            int r = wr * 64 + m * 16 + fr;
            int c0 = (2 * g)     ^ (r & 7);
            int c1 = (2 * g + 1) ^ (r & 7);
            int4 lo = *(const int4*)(As + r * 128 + c0 * 16);
            int4 hi = *(const int4*)(As + r * 128 + c1 * 16);
            a[m] = (intx8){lo.x, lo.y, lo.z, lo.w, hi.x, hi.y, hi.z, hi.w};
        }
        #pragma unroll
        for (int n = 0; n < 4; ++n) {
            int r = wc * 64 + n * 16 + fr;
            int c0 = (2 * g)     ^ (r & 7);
            int c1 = (2 * g + 1) ^ (r & 7);
            int4 lo = *(const int4*)(Bs + r * 128 + c0 * 16);
            int4 hi = *(const int4*)(Bs + r * 128 + c1 * 16);
            b[n] = (intx8){lo.x, lo.y, lo.z, lo.w, hi.x, hi.y, hi.z, hi.w};
        }
        #pragma unroll
        for (int m = 0; m < 4; ++m)
            #pragma unroll
            for (int n = 0; n < 4; ++n)
                acc[m][n] = __builtin_amdgcn_mfma_scale_f32_16x16x128_f8f6f4(
                    a[m], b[n], acc[m][n], 0, 0,           // cbsz=fp8, blgp=fp8
                    0, 0x7F7F7F7F, 0, 0x7F7F7F7F);         // E8M0 scales = 1.0
    }

    // epilogue: C/D layout (shape-determined): col=lane&15, row=(lane>>4)*4+j
    float wsv = *wscale;
    int crow = g * 4;
    int ccol = fr;
    float bv[4];
    #pragma unroll
    for (int n = 0; n < 4; ++n) bv[n] = bias[col0 + wc * 64 + n * 16 + ccol];
    #pragma unroll
    for (int m = 0; m < 4; ++m) {
        int r = row0 + wr * 64 + m * 16 + crow;
        #pragma unroll
        for (int n = 0; n < 4; ++n) {
            int c = col0 + wc * 64 + n * 16 + ccol;
            #pragma unroll
            for (int j = 0; j < 4; ++j)
                C[(long)(r + j) * N + c] = acc[m][n][j] * wsv + bv[n];
        }
    }
}

extern "C" void kernel_launch(void* const* d_in, const int* in_sizes, int n_in,
                              void* d_out, int out_size, void* d_ws, size_t ws_size,
                              hipStream_t stream) {
    const float* x      = (const float*)d_in[0];
    const float* w      = (const float*)d_in[1];
    const float* wscale = (const float*)d_in[2];
    const float* bias   = (const float*)d_in[3];
    float* out = (float*)d_out;

    const int K = 2048, N = 2048;
    const int M = in_sizes[0] / K;     // 16384

    unsigned char* ws = (unsigned char*)d_ws;
    unsigned* amax = (unsigned*)ws;                          // 4 B
    int* wq = (int*)(ws + 1024);                             // N*K   = 4.2 MB fp8
    int* xq = (int*)(ws + 1024 + (size_t)N * K);             // M*K   = 33.5 MB fp8

    hipMemsetAsync(amax, 0, 4, stream);
    k_pre<<<2048, 256, 0, stream>>>(x, amax, (M * K) / 4, w, wq, (N * K) / 16);
    k_quant_x<<<2048, 256, 0, stream>>>(x, xq, amax, (M * K) / 16);

    int grid = (M / BM) * (N / BN);    // 128 * 16 = 2048
    k_gemm_mx<<<grid, 256, 0, stream>>>((const unsigned char*)xq, (const unsigned char*)wq,
                                        bias, wscale, out, M, N, K);
}